// Round 1
// baseline (655.277 us; speedup 1.0000x reference)
//
#include <hip/hip_runtime.h>

#define NGRAPH 1024
#define NPG 128
#define NTOT (NGRAPH*NPG)
#define EPG 2048
#define ETOT (NTOT*16)
#define HD 64

__device__ __forceinline__ int swz(int r, int k){ return (r<<6) | ((k + r) & 63); }
__device__ __forceinline__ float lrelu(float x, float s){ return x > 0.f ? x : s*x; }

// ---------------- kernel 1: one block per 128-node graph ----------------
__global__ __launch_bounds__(256) void gnn_fused(
    const float* __restrict__ x, const int* __restrict__ ei,
    const float* __restrict__ Wl, const float* __restrict__ bl,
    const float* __restrict__ Wr, const float* __restrict__ br,
    const float* __restrict__ att, const float* __restrict__ bv2,
    const float* __restrict__ Wg1, const float* __restrict__ as1,
    const float* __restrict__ ad1, const float* __restrict__ bg1,
    const float* __restrict__ Wg2, const float* __restrict__ as2,
    const float* __restrict__ ad2, const float* __restrict__ bg2,
    const float* __restrict__ lng, const float* __restrict__ lnb,
    float* __restrict__ hout)
{
  __shared__ float sA[NPG*HD];          // 32 KB: xr -> h -> out
  __shared__ float sB[NPG*HD];          // 32 KB: xl / xw
  __shared__ float eva[EPG];            // 8 KB: per-edge logits -> exp
  __shared__ unsigned char esrc[EPG];   // CSR src (sorted by dst)
  __shared__ unsigned char edst[EPG];   // CSR dst
  __shared__ int soff[NPG+1];
  __shared__ int spos[NPG];
  __shared__ float nmv[NPG];            // 1/(sum+eps)
  __shared__ float sse[NPG];            // self-loop exp (GAT layers)
  __shared__ float als[NPG];
  __shared__ float ald[NPG];
  __shared__ float satt[HD];

  const int g    = blockIdx.x;
  const int tid  = threadIdx.x;
  const int lane = tid & 63;
  const int wv   = tid >> 6;
  const int ebase = g * EPG;

  // ---- CSR build ----
  if (tid < NPG) spos[tid] = 0;
  if (tid < HD)  satt[tid] = att[tid];
  __syncthreads();
  for (int e = tid; e < EPG; e += 256)
    atomicAdd(&spos[ei[ETOT + ebase + e] - g*NPG], 1);
  __syncthreads();
  if (tid == 0)  soff[0] = 0;
  if (tid < NPG) soff[tid+1] = spos[tid];
  __syncthreads();
  for (int st = 1; st < NPG; st <<= 1) {       // Hillis-Steele inclusive scan
    int v = 0;
    if (tid < NPG && tid >= st) v = soff[tid+1-st];
    __syncthreads();
    if (tid < NPG && tid >= st) soff[tid+1] += v;
    __syncthreads();
  }
  if (tid < NPG) spos[tid] = soff[tid];
  __syncthreads();
  for (int e = tid; e < EPG; e += 256) {
    int s = ei[ebase + e] - g*NPG;
    int d = ei[ETOT + ebase + e] - g*NPG;
    int p = atomicAdd(&spos[d], 1);
    esrc[p] = (unsigned char)s;
    edst[p] = (unsigned char)d;
  }

  // ---- GATv2 linear transforms: xl -> sB, xr -> sA ----
  {
    const float* xg = x + (size_t)g * NPG * 4;
    float wl0=Wl[lane], wl1=Wl[64+lane], wl2=Wl[128+lane], wl3=Wl[192+lane];
    float wr0=Wr[lane], wr1=Wr[64+lane], wr2=Wr[128+lane], wr3=Wr[192+lane];
    float bbl=bl[lane], bbr=br[lane];
    __syncthreads();   // also covers CSR scatter
    for (int i = wv; i < NPG; i += 4) {
      float x0=xg[i*4+0], x1=xg[i*4+1], x2=xg[i*4+2], x3=xg[i*4+3];
      sB[swz(i,lane)] = bbl + x0*wl0 + x1*wl1 + x2*wl2 + x3*wl3;
      sA[swz(i,lane)] = bbr + x0*wr0 + x1*wr1 + x2*wr2 + x3*wr3;
    }
  }
  __syncthreads();

  // ---- GATv2 edge logits: att . leaky(xl[s]+xr[d]) ----
  for (int p = tid; p < EPG; p += 256) {
    int s = esrc[p], d = edst[p];
    float acc = 0.f;
    #pragma unroll 8
    for (int k = 0; k < HD; k++) {
      float v = sB[swz(s,k)] + sA[swz(d,k)];
      acc += lrelu(v, 0.2f) * satt[k];
    }
    eva[p] = acc;
  }
  __syncthreads();

  // ---- GATv2 softmax per dst (no self-loop) ----
  if (tid < NPG) {
    int p0 = soff[tid], p1 = soff[tid+1];
    float m = -1e30f;
    for (int p = p0; p < p1; p++) m = fmaxf(m, eva[p]);
    float s = 0.f;
    for (int p = p0; p < p1; p++) { float ex = __expf(eva[p]-m); eva[p]=ex; s+=ex; }
    nmv[tid] = 1.f / (s + 1e-16f);
  }
  __syncthreads();

  // ---- GATv2 aggregate + bias + leaky(0.01) -> sA ----
  {
    float bk = bv2[lane];
    for (int idx = tid; idx < NPG*HD; idx += 256) {
      int d = idx >> 6;
      int p0 = soff[d], p1 = soff[d+1];
      float acc = 0.f;
      for (int p = p0; p < p1; p++) acc += eva[p] * sB[swz(esrc[p], lane)];
      sA[swz(d,lane)] = lrelu(acc * nmv[d] + bk, 0.01f);
    }
  }
  __syncthreads();

  // ---- LayerNorm (wave per node) ----
  {
    float gv = lng[lane], bv = lnb[lane];
    for (int d = wv; d < NPG; d += 4) {
      float v = sA[swz(d,lane)];
      float s1 = v, s2 = v*v;
      #pragma unroll
      for (int m = 32; m > 0; m >>= 1) { s1 += __shfl_xor(s1, m); s2 += __shfl_xor(s2, m); }
      float mu  = s1 * 0.015625f;
      float var = s2 * 0.015625f - mu*mu;
      float rs  = rsqrtf(var + 1e-5f);
      sA[swz(d,lane)] = (v - mu) * rs * gv + bv;
    }
  }
  __syncthreads();

  // ---- two GATConv layers (with self-loops) ----
  for (int layer = 0; layer < 2; layer++) {
    const float* Wg  = layer ? Wg2 : Wg1;
    const float* avs = layer ? as2 : as1;
    const float* avd = layer ? ad2 : ad1;
    const float* bg  = layer ? bg2 : bg1;

    // xw = h @ Wg -> sB  (lane = row, wave-uniform j-block, W via scalar loads)
    {
      int jb = __builtin_amdgcn_readfirstlane(wv) * 16;
      float acc0[16], acc1[16];
      #pragma unroll
      for (int jj=0;jj<16;jj++){ acc0[jj]=0.f; acc1[jj]=0.f; }
      for (int k = 0; k < HD; k++) {
        float a0 = sA[swz(lane,k)];
        float a1 = sA[swz(lane+64,k)];
        #pragma unroll
        for (int jj=0;jj<16;jj++){
          float w = Wg[k*HD + jb + jj];
          acc0[jj] += a0*w; acc1[jj] += a1*w;
        }
      }
      #pragma unroll
      for (int jj=0;jj<16;jj++){
        sB[swz(lane,    jb+jj)] = acc0[jj];
        sB[swz(lane+64, jb+jj)] = acc1[jj];
      }
    }
    __syncthreads();

    // per-node attention halves
    {
      float ws_ = avs[lane], wd_ = avd[lane];
      for (int d = wv; d < NPG; d += 4) {
        float v = sB[swz(d,lane)];
        float s1 = v*ws_, s2 = v*wd_;
        #pragma unroll
        for (int m = 32; m > 0; m >>= 1) { s1 += __shfl_xor(s1, m); s2 += __shfl_xor(s2, m); }
        if (lane == 0) { als[d] = s1; ald[d] = s2; }
      }
    }
    __syncthreads();

    // scalar edge logits
    for (int p = tid; p < EPG; p += 256)
      eva[p] = lrelu(als[esrc[p]] + ald[edst[p]], 0.2f);
    __syncthreads();

    // softmax per dst including self-loop
    if (tid < NPG) {
      int p0 = soff[tid], p1 = soff[tid+1];
      float se = lrelu(als[tid] + ald[tid], 0.2f);
      float m = se;
      for (int p = p0; p < p1; p++) m = fmaxf(m, eva[p]);
      float ex0 = __expf(se - m);
      sse[tid] = ex0;
      float s = ex0;
      for (int p = p0; p < p1; p++) { float ex = __expf(eva[p]-m); eva[p]=ex; s+=ex; }
      nmv[tid] = 1.f / (s + 1e-16f);
    }
    __syncthreads();

    // aggregate (incl self) + bias + relu -> sA
    {
      float bk = bg[lane];
      for (int idx = tid; idx < NPG*HD; idx += 256) {
        int d = idx >> 6;
        int p0 = soff[d], p1 = soff[d+1];
        float acc = sse[d] * sB[swz(d, lane)];
        for (int p = p0; p < p1; p++) acc += eva[p] * sB[swz(esrc[p], lane)];
        float v = acc * nmv[d] + bk;
        sA[swz(d,lane)] = v > 0.f ? v : 0.f;
      }
    }
    __syncthreads();
  }

  // ---- write h (already in reshape-flat order) ----
  float* hg = hout + (size_t)g * NPG * HD;
  for (int idx = tid; idx < NPG*HD; idx += 256)
    hg[idx] = sA[swz(idx>>6, idx&63)];
}

// ---------------- kernel 2: head GEMM, split-K with atomic partials ----------------
__global__ __launch_bounds__(256) void head_gemm(
    const float* __restrict__ hbuf, const float* __restrict__ W1,
    float* __restrict__ partial)
{
  __shared__ float sAA[16*64];
  __shared__ float sBB[64*128];
  const int tid = threadIdx.x;
  const int g0 = blockIdx.x * 16;
  const int k0 = blockIdx.y * 1024;
  const int j  = tid & 127;
  const int rh = tid >> 7;
  float acc[8];
  #pragma unroll
  for (int r=0;r<8;r++) acc[r]=0.f;
  for (int c = 0; c < 16; c++) {
    int kc = k0 + c*64;
    for (int idx = tid; idx < 1024; idx += 256)
      sAA[idx] = hbuf[(size_t)(g0 + (idx>>6))*8192 + kc + (idx&63)];
    for (int idx = tid; idx < 8192; idx += 256)
      sBB[idx] = W1[(size_t)kc*128 + idx];
    __syncthreads();
    for (int kk = 0; kk < 64; kk++) {
      float b = sBB[kk*128 + j];
      #pragma unroll
      for (int r=0;r<8;r++)
        acc[r] += sAA[(rh*8+r)*64 + kk] * b;
    }
    __syncthreads();
  }
  #pragma unroll
  for (int r=0;r<8;r++)
    atomicAdd(&partial[(g0 + rh*8 + r)*128 + j], acc[r]);
}

// ---------------- kernel 3: bias + leaky + W2 dot + sigmoid ----------------
__global__ __launch_bounds__(64) void head_out(
    const float* __restrict__ partial, const float* __restrict__ b1,
    const float* __restrict__ W2, const float* __restrict__ b2,
    float* __restrict__ out)
{
  const int g = blockIdx.x;
  const int l = threadIdx.x;
  float v0 = lrelu(partial[g*128 + l]      + b1[l],      0.01f) * W2[l];
  float v1 = lrelu(partial[g*128 + 64 + l] + b1[64 + l], 0.01f) * W2[64 + l];
  float s = v0 + v1;
  #pragma unroll
  for (int m = 32; m > 0; m >>= 1) s += __shfl_xor(s, m);
  if (l == 0) out[g] = 1.f / (1.f + __expf(-(s + b2[0])));
}

extern "C" void kernel_launch(void* const* d_in, const int* in_sizes, int n_in,
                              void* d_out, int out_size, void* d_ws, size_t ws_size,
                              hipStream_t stream) {
  const float* x   = (const float*)d_in[0];
  const int*   ei  = (const int*)  d_in[1];
  const float* Wl  = (const float*)d_in[2];
  const float* bl_ = (const float*)d_in[3];
  const float* Wr  = (const float*)d_in[4];
  const float* br_ = (const float*)d_in[5];
  const float* att = (const float*)d_in[6];
  const float* bv2 = (const float*)d_in[7];
  const float* Wg1 = (const float*)d_in[8];
  const float* as1 = (const float*)d_in[9];
  const float* ad1 = (const float*)d_in[10];
  const float* bg1 = (const float*)d_in[11];
  const float* Wg2 = (const float*)d_in[12];
  const float* as2 = (const float*)d_in[13];
  const float* ad2 = (const float*)d_in[14];
  const float* bg2 = (const float*)d_in[15];
  const float* lng = (const float*)d_in[16];
  const float* lnb = (const float*)d_in[17];
  const float* W1  = (const float*)d_in[18];
  const float* b1  = (const float*)d_in[19];
  const float* W2  = (const float*)d_in[20];
  const float* b2  = (const float*)d_in[21];
  float* out = (float*)d_out;

  float* hbuf    = (float*)d_ws;                                    // 1024*128*64 f32 = 32 MB
  float* partial = (float*)((char*)d_ws + (size_t)NTOT*HD*sizeof(float)); // 1024*128 f32

  hipMemsetAsync(partial, 0, (size_t)NGRAPH*128*sizeof(float), stream);
  gnn_fused<<<NGRAPH, 256, 0, stream>>>(x, ei, Wl, bl_, Wr, br_, att, bv2,
      Wg1, as1, ad1, bg1, Wg2, as2, ad2, bg2, lng, lnb, hbuf);
  head_gemm<<<dim3(64, 8), 256, 0, stream>>>(hbuf, W1, partial);
  head_out<<<NGRAPH, 64, 0, stream>>>(partial, b1, W2, b2, out);
}

// Round 2
// 366.820 us; speedup vs baseline: 1.7864x; 1.7864x over previous
//
#include <hip/hip_runtime.h>
#include <hip/hip_bf16.h>

#define NGRAPH 1024
#define NPG 128
#define NTOT (NGRAPH*NPG)
#define EPG 2048
#define ETOT (NTOT*16)
#define HD 64

typedef unsigned int uint;
typedef unsigned short ushort_t;

__device__ __forceinline__ float lrelu(float x, float s){ return fmaxf(x, x*s); }
__device__ __forceinline__ float b2lo(uint u){ return __uint_as_float(u << 16); }
__device__ __forceinline__ float b2hi(uint u){ return __uint_as_float(u & 0xFFFF0000u); }
__device__ __forceinline__ uint pkbf(float a, float b){
  union { __hip_bfloat162 h; uint u; } t;
  t.h = __hip_bfloat162{__float2bfloat16(a), __float2bfloat16(b)};
  return t.u;
}
// DPP add: disabled/invalid source lanes contribute 0
#define DPP_ADD(v, ctrl) ((v) + __int_as_float(__builtin_amdgcn_update_dpp(0, __float_as_int(v), (ctrl), 0xF, 0xF, false)))
__device__ __forceinline__ float wsum64(float v){
  v = DPP_ADD(v, 0x111); v = DPP_ADD(v, 0x112); v = DPP_ADD(v, 0x114); v = DPP_ADD(v, 0x118);
  v = DPP_ADD(v, 0x142); v = DPP_ADD(v, 0x143);          // row_bcast:15, row_bcast:31
  return __int_as_float(__builtin_amdgcn_readlane(__float_as_int(v), 63));
}

// f32 buffer sA: row r (64 f32), quad-XOR swizzle -> any full-row wave access conflict-free
__device__ __forceinline__ int qswz(int r, int k){
  return (r<<6) + ((((k>>2) ^ (r & 15))<<2) | (k & 3));
}
__device__ __forceinline__ int qbase(int r, int kq){ return (r<<6) + (((kq) ^ (r & 15))<<2); }
// bf16 buffer: row r = 32 u32 pair-words, octet(4-word)-XOR swizzle
__device__ __forceinline__ int obase(int r, int oc){ return (r<<5) + (((oc) ^ (r & 7))<<2); }
__device__ __forceinline__ int oswz(int r, int p){
  return (r<<5) + ((((p>>2) ^ (r & 7))<<2) | (p & 3));
}

__global__ __launch_bounds__(256) void gnn_fused(
    const float* __restrict__ x, const int* __restrict__ ei,
    const float* __restrict__ Wl, const float* __restrict__ bl,
    const float* __restrict__ Wr, const float* __restrict__ br,
    const float* __restrict__ att, const float* __restrict__ bv2,
    const float* __restrict__ Wg1, const float* __restrict__ as1,
    const float* __restrict__ ad1, const float* __restrict__ bg1,
    const float* __restrict__ Wg2, const float* __restrict__ as2,
    const float* __restrict__ ad2, const float* __restrict__ bg2,
    const float* __restrict__ lng, const float* __restrict__ lnb,
    uint* __restrict__ hout)
{
  // 64516 B static LDS (< 64 KiB static limit; 2 blocks/CU)
  __shared__ uint SM[16132];
  float*    sA   = (float*)SM;            // [8192] f32 h / accum (quad-swz)
  uint*     sXr  = SM;                    // [4096] alias: xr bf16 (octet-swz), phase-1 only
  uint*     sB   = SM + 8192;             // [4096] gather-side bf16 (xl / xw)
  float*    eva  = (float*)(SM + 12288);  // [2048] raw logits
  uint*     evp  = SM + 12288;            // alias: packed (ex & ~0xFF) | src
  float*    alsP = (float*)(SM + 12288);  // alias: xw attention partials [1024]
  ushort_t* edsd = (ushort_t*)(SM + 14336); // [2048] s | d<<8 (CSR order)
  int*      soff = (int*)(SM + 15360);    // [129]
  int*      spos = soff + 129;            // [128]
  float*    nmv  = (float*)(spos + 128);  // [128]
  float*    sse  = nmv + 128;             // [128]
  float*    als  = sse + 128;             // [128]
  float*    ald  = als + 128;             // [128]

  const int g    = blockIdx.x;
  const int tid  = threadIdx.x;
  const int lane = tid & 63;
  const int wv   = tid >> 6;
  const int ebase = g * EPG;
  const int oc   = lane & 7;       // octet (8 bf16 = 8 k's) within a row
  const int grp  = lane >> 3;      // 8-lane group id (0..7)

  // ---------------- CSR build ----------------
  if (tid < NPG) spos[tid] = 0;
  __syncthreads();
  for (int e = tid; e < EPG; e += 256)
    atomicAdd(&spos[ei[ETOT + ebase + e] - g*NPG], 1);
  __syncthreads();
  if (wv == 0) {
    int c0 = spos[lane], c1 = spos[lane + 64];
    #pragma unroll
    for (int o = 1; o < 64; o <<= 1) { int t = __shfl_up(c0, o); if (lane >= o) c0 += t; }
    #pragma unroll
    for (int o = 1; o < 64; o <<= 1) { int t = __shfl_up(c1, o); if (lane >= o) c1 += t; }
    int tot0 = __shfl(c0, 63);
    soff[lane + 1]  = c0;
    soff[lane + 65] = c1 + tot0;
    if (lane == 0) soff[0] = 0;
  }
  __syncthreads();
  if (tid < NPG) spos[tid] = soff[tid];
  __syncthreads();
  for (int e = tid; e < EPG; e += 256) {
    int s = ei[ebase + e] - g*NPG;
    int d = ei[ETOT + ebase + e] - g*NPG;
    int p = atomicAdd(&spos[d], 1);
    edsd[p] = (ushort_t)(s | (d << 8));
  }
  __syncthreads();

  // ---------------- GATv2 transforms: xl -> sB (bf16), xr -> sXr (bf16) ----------------
  {
    const int pl = lane & 31, hb = lane >> 5;   // pl = k-pair, two rows per wave step
    const float2 wl0 = *(const float2*)&Wl[0*64 + 2*pl];
    const float2 wl1 = *(const float2*)&Wl[1*64 + 2*pl];
    const float2 wl2 = *(const float2*)&Wl[2*64 + 2*pl];
    const float2 wl3 = *(const float2*)&Wl[3*64 + 2*pl];
    const float2 wr0 = *(const float2*)&Wr[0*64 + 2*pl];
    const float2 wr1 = *(const float2*)&Wr[1*64 + 2*pl];
    const float2 wr2 = *(const float2*)&Wr[2*64 + 2*pl];
    const float2 wr3 = *(const float2*)&Wr[3*64 + 2*pl];
    const float2 blp = *(const float2*)&bl[2*pl];
    const float2 brp = *(const float2*)&br[2*pl];
    const float4* x4 = (const float4*)x + (size_t)g * NPG;
    for (int st = 0; st < 16; st++) {
      int i = st*8 + wv*2 + hb;
      float4 xi = x4[i];
      float l0 = blp.x + xi.x*wl0.x + xi.y*wl1.x + xi.z*wl2.x + xi.w*wl3.x;
      float l1 = blp.y + xi.x*wl0.y + xi.y*wl1.y + xi.z*wl2.y + xi.w*wl3.y;
      float r0 = brp.x + xi.x*wr0.x + xi.y*wr1.x + xi.z*wr2.x + xi.w*wr3.x;
      float r1 = brp.y + xi.x*wr0.y + xi.y*wr1.y + xi.z*wr2.y + xi.w*wr3.y;
      sB [oswz(i, pl)] = pkbf(l0, l1);
      sXr[oswz(i, pl)] = pkbf(r0, r1);
    }
  }
  __syncthreads();

  // ---------------- GATv2 edge logits (8-lane groups, b128 bf16 gathers) ----------------
  {
    float4 atA = *(const float4*)&att[oc*8];
    float4 atB = *(const float4*)&att[oc*8 + 4];
    int base = wv * 512;
    for (int stp = 0; stp < 64; stp++) {
      int e  = base + stp*8 + grp;
      int sd = edsd[e];
      int s  = sd & 127, d = sd >> 8;
      uint4 ql = *(uint4*)&sB [obase(s, oc)];
      uint4 qr = *(uint4*)&sXr[obase(d, oc)];
      float acc;
      float v;
      v = b2lo(ql.x)+b2lo(qr.x); acc  = lrelu(v,0.2f)*atA.x;
      v = b2hi(ql.x)+b2hi(qr.x); acc += lrelu(v,0.2f)*atA.y;
      v = b2lo(ql.y)+b2lo(qr.y); acc += lrelu(v,0.2f)*atA.z;
      v = b2hi(ql.y)+b2hi(qr.y); acc += lrelu(v,0.2f)*atA.w;
      v = b2lo(ql.z)+b2lo(qr.z); acc += lrelu(v,0.2f)*atB.x;
      v = b2hi(ql.z)+b2hi(qr.z); acc += lrelu(v,0.2f)*atB.y;
      v = b2lo(ql.w)+b2lo(qr.w); acc += lrelu(v,0.2f)*atB.z;
      v = b2hi(ql.w)+b2hi(qr.w); acc += lrelu(v,0.2f)*atB.w;
      acc = DPP_ADD(acc, 0x111); acc = DPP_ADD(acc, 0x112); acc = DPP_ADD(acc, 0x114);
      if ((lane & 7) == 7) eva[e] = acc;   // group sum lands at top lane
    }
  }
  __syncthreads();

  // ---------------- softmax + pack (16 lanes / node); layer-generic ----------------
  // self=false: GATv2.  Writes evp[p] = (bits(ex) & ~0xFF) | src, nmv[d], (sse[d])
  {
    const int g16 = tid >> 4, sl = tid & 15;
    for (int it = 0; it < 8; it++) {
      int d = it*16 + g16;
      int p0 = soff[d], p1 = soff[d+1];
      float m = -1e30f;
      for (int p = p0 + sl; p < p1; p += 16) m = fmaxf(m, eva[p]);
      #pragma unroll
      for (int o = 1; o < 16; o <<= 1) m = fmaxf(m, __shfl_xor(m, o));
      float ssum = 0.f;
      for (int p = p0 + sl; p < p1; p += 16) {
        int s = edsd[p] & 127;
        float ex = __expf(eva[p] - m);
        ssum += ex;
        evp[p] = (__float_as_uint(ex) & 0xFFFFFF00u) | (uint)s;
      }
      #pragma unroll
      for (int o = 1; o < 16; o <<= 1) ssum += __shfl_xor(ssum, o);
      if (sl == 0) nmv[d] = 1.f / (ssum + 1e-16f);
    }
  }
  __syncthreads();

  // ---------------- GATv2 aggregate -> sA (f32), + bias, leaky 0.01 ----------------
  {
    float4 bA = *(const float4*)&bv2[oc*8];
    float4 bB = *(const float4*)&bv2[oc*8 + 4];
    for (int pass = 0; pass < 4; pass++) {
      int d  = wv*32 + pass*8 + grp;
      int p0 = soff[d], p1 = soff[d+1];
      float a0=0,a1=0,a2=0,a3=0,a4=0,a5=0,a6=0,a7=0;
      for (int j = 0; ; j++) {
        int p = p0 + j;
        bool act = p < p1;
        if (!__any(act)) break;
        uint pv = evp[act ? p : 0];
        float aw = act ? __uint_as_float(pv & 0xFFFFFF00u) : 0.f;
        int s = pv & 127;
        uint4 q = *(uint4*)&sB[obase(s, oc)];
        a0 += aw*b2lo(q.x); a1 += aw*b2hi(q.x);
        a2 += aw*b2lo(q.y); a3 += aw*b2hi(q.y);
        a4 += aw*b2lo(q.z); a5 += aw*b2hi(q.z);
        a6 += aw*b2lo(q.w); a7 += aw*b2hi(q.w);
      }
      float nm = nmv[d];
      float4 o1, o2;
      o1.x = lrelu(a0*nm + bA.x, 0.01f); o1.y = lrelu(a1*nm + bA.y, 0.01f);
      o1.z = lrelu(a2*nm + bA.z, 0.01f); o1.w = lrelu(a3*nm + bA.w, 0.01f);
      o2.x = lrelu(a4*nm + bB.x, 0.01f); o2.y = lrelu(a5*nm + bB.y, 0.01f);
      o2.z = lrelu(a6*nm + bB.z, 0.01f); o2.w = lrelu(a7*nm + bB.w, 0.01f);
      *(float4*)&sA[qbase(d, 2*oc)]     = o1;
      *(float4*)&sA[qbase(d, 2*oc + 1)] = o2;
    }
  }
  __syncthreads();

  // ---------------- LayerNorm (wave per node, DPP reduce) ----------------
  {
    float gv = lng[lane], bv = lnb[lane];
    for (int d = wv; d < NPG; d += 4) {
      float v  = sA[qswz(d, lane)];
      float s1 = wsum64(v);
      float s2 = wsum64(v*v);
      float mu  = s1 * 0.015625f;
      float var = s2 * 0.015625f - mu*mu;
      sA[qswz(d, lane)] = (v - mu) * rsqrtf(var + 1e-5f) * gv + bv;
    }
  }
  __syncthreads();

  // ---------------- two GATConv layers ----------------
  for (int layer = 0; layer < 2; layer++) {
    const float* Wg  = layer ? Wg2 : Wg1;
    const float* avs = layer ? as2 : as1;
    const float* avd = layer ? ad2 : ad1;
    const float* bg  = layer ? bg2 : bg1;

    // xw = h @ Wg -> sB (bf16) ; fused als/ald partials -> alsP (evp region)
    {
      int jb = __builtin_amdgcn_readfirstlane(wv) * 16;
      float acc0[16], acc1[16];
      #pragma unroll
      for (int jj=0;jj<16;jj++){ acc0[jj]=0.f; acc1[jj]=0.f; }
      int r0 = lane, r1 = lane + 64;
      for (int kq = 0; kq < 16; kq++) {
        float4 aq0 = *(float4*)&sA[qbase(r0, kq)];
        float4 aq1 = *(float4*)&sA[qbase(r1, kq)];
        const float* w0 = Wg + (kq*4+0)*64 + jb;
        const float* w1 = Wg + (kq*4+1)*64 + jb;
        const float* w2 = Wg + (kq*4+2)*64 + jb;
        const float* w3 = Wg + (kq*4+3)*64 + jb;
        #pragma unroll
        for (int jj=0;jj<16;jj++){
          acc0[jj] += aq0.x*w0[jj] + aq0.y*w1[jj] + aq0.z*w2[jj] + aq0.w*w3[jj];
          acc1[jj] += aq1.x*w0[jj] + aq1.y*w1[jj] + aq1.z*w2[jj] + aq1.w*w3[jj];
        }
      }
      float pa0=0,pd0=0,pa1=0,pd1=0;
      #pragma unroll
      for (int jj=0;jj<16;jj++){
        float ws_ = avs[jb+jj], wd_ = avd[jb+jj];
        pa0 += acc0[jj]*ws_; pd0 += acc0[jj]*wd_;
        pa1 += acc1[jj]*ws_; pd1 += acc1[jj]*wd_;
      }
      __syncthreads();   // evp consumed by previous aggregate; safe to overwrite
      #pragma unroll
      for (int t=0;t<8;t++){
        sB[oswz(r0, 8*wv + t)] = pkbf(acc0[2*t], acc0[2*t+1]);
        sB[oswz(r1, 8*wv + t)] = pkbf(acc1[2*t], acc1[2*t+1]);
      }
      alsP[wv*128 + r0]       = pa0;  alsP[wv*128 + r1]       = pa1;
      alsP[512 + wv*128 + r0] = pd0;  alsP[512 + wv*128 + r1] = pd1;
    }
    __syncthreads();
    if (tid < 128) {
      als[tid] = alsP[tid] + alsP[128+tid] + alsP[256+tid] + alsP[384+tid];
    } else {
      int t = tid - 128;
      ald[t] = alsP[512+t] + alsP[640+t] + alsP[768+t] + alsP[896+t];
    }
    __syncthreads();

    // scalar edge logits (overwrites alsP region as eva)
    for (int i = 0; i < 8; i++) {
      int e = tid + i*256;
      int sd = edsd[e];
      eva[e] = lrelu(als[sd & 127] + ald[sd >> 8], 0.2f);
    }
    __syncthreads();

    // softmax incl. self-loop
    {
      const int g16 = tid >> 4, sl = tid & 15;
      for (int it = 0; it < 8; it++) {
        int d = it*16 + g16;
        int p0 = soff[d], p1 = soff[d+1];
        float se = lrelu(als[d] + ald[d], 0.2f);
        float m = se;
        for (int p = p0 + sl; p < p1; p += 16) m = fmaxf(m, eva[p]);
        #pragma unroll
        for (int o = 1; o < 16; o <<= 1) m = fmaxf(m, __shfl_xor(m, o));
        float ex0 = __expf(se - m);
        float ssum = 0.f;
        for (int p = p0 + sl; p < p1; p += 16) {
          int s = edsd[p] & 127;
          float ex = __expf(eva[p] - m);
          ssum += ex;
          evp[p] = (__float_as_uint(ex) & 0xFFFFFF00u) | (uint)s;
        }
        #pragma unroll
        for (int o = 1; o < 16; o <<= 1) ssum += __shfl_xor(ssum, o);
        if (sl == 0) { nmv[d] = 1.f / (ssum + ex0 + 1e-16f); sse[d] = ex0; }
      }
    }
    __syncthreads();

    // aggregate incl. self + bias + relu -> sA
    {
      float4 bA = *(const float4*)&bg[oc*8];
      float4 bB = *(const float4*)&bg[oc*8 + 4];
      for (int pass = 0; pass < 4; pass++) {
        int d  = wv*32 + pass*8 + grp;
        int p0 = soff[d], p1 = soff[d+1];
        float a0=0,a1=0,a2=0,a3=0,a4=0,a5=0,a6=0,a7=0;
        for (int j = 0; ; j++) {
          int p = p0 + j;
          bool act = p < p1;
          if (!__any(act)) break;
          uint pv = evp[act ? p : 0];
          float aw = act ? __uint_as_float(pv & 0xFFFFFF00u) : 0.f;
          int s = pv & 127;
          uint4 q = *(uint4*)&sB[obase(s, oc)];
          a0 += aw*b2lo(q.x); a1 += aw*b2hi(q.x);
          a2 += aw*b2lo(q.y); a3 += aw*b2hi(q.y);
          a4 += aw*b2lo(q.z); a5 += aw*b2hi(q.z);
          a6 += aw*b2lo(q.w); a7 += aw*b2hi(q.w);
        }
        { // self-loop
          float e0 = sse[d];
          uint4 q = *(uint4*)&sB[obase(d, oc)];
          a0 += e0*b2lo(q.x); a1 += e0*b2hi(q.x);
          a2 += e0*b2lo(q.y); a3 += e0*b2hi(q.y);
          a4 += e0*b2lo(q.z); a5 += e0*b2hi(q.z);
          a6 += e0*b2lo(q.w); a7 += e0*b2hi(q.w);
        }
        float nm = nmv[d];
        float4 o1, o2;
        o1.x = fmaxf(a0*nm + bA.x, 0.f); o1.y = fmaxf(a1*nm + bA.y, 0.f);
        o1.z = fmaxf(a2*nm + bA.z, 0.f); o1.w = fmaxf(a3*nm + bA.w, 0.f);
        o2.x = fmaxf(a4*nm + bB.x, 0.f); o2.y = fmaxf(a5*nm + bB.y, 0.f);
        o2.z = fmaxf(a6*nm + bB.z, 0.f); o2.w = fmaxf(a7*nm + bB.w, 0.f);
        *(float4*)&sA[qbase(d, 2*oc)]     = o1;
        *(float4*)&sA[qbase(d, 2*oc + 1)] = o2;
      }
    }
    __syncthreads();
  }

  // ---------------- write h as packed bf16 pairs ----------------
  {
    uint* hg = hout + (size_t)g * 4096;
    for (int it = 0; it < 16; it++) {
      int idx = tid + it*256;            // pair index: r*32 + pl
      int r = idx >> 5, pl = idx & 31, k0 = 2*pl;
      float2 rd = *(float2*)&sA[qswz(r, k0)];   // k0 even -> (k0,k0+1) same quad
      hg[idx] = pkbf(rd.x, rd.y);
    }
  }
}

// ---------------- head GEMM: [1024 x 8192(bf16)] @ W1[8192 x 128], K split 16 ----------------
__global__ __launch_bounds__(256) void head_gemm(
    const uint* __restrict__ hbuf, const float* __restrict__ W1,
    float* __restrict__ partial)
{
  __shared__ float    sBB[64*128];     // 32 KB
  __shared__ ushort_t sAt[64*72];      // 9 KB, A transposed [k][row], pad 72
  const int tid = threadIdx.x;
  const int g0  = blockIdx.x * 64;
  const int kc0 = blockIdx.y * 512;
  const int ty = tid >> 5;             // 0..7  -> rows ty*8..+7
  const int tx = tid & 31;             // 0..31 -> cols tx*4..+3
  float acc[8][4];
  #pragma unroll
  for (int i=0;i<8;i++){ acc[i][0]=0;acc[i][1]=0;acc[i][2]=0;acc[i][3]=0; }

  for (int ch = 0; ch < 8; ch++) {
    // stage A (bf16 pairs -> transposed u16)
    #pragma unroll
    for (int i = 0; i < 8; i++) {
      int idx = tid + i*256;           // 2048 pairs: 64 rows x 32 pairs
      int r = idx >> 5, c = idx & 31;
      uint u = hbuf[(size_t)(g0 + r)*4096 + (kc0 >> 1) + ch*32 + c];
      sAt[(2*c)*72 + r]   = (ushort_t)(u & 0xFFFFu);
      sAt[(2*c+1)*72 + r] = (ushort_t)(u >> 16);
    }
    // stage B
    #pragma unroll
    for (int i = 0; i < 8; i++) {
      int idx = tid + i*256;           // 2048 float4
      int row = idx >> 5, c4 = (idx & 31)*4;
      *(float4*)&sBB[row*128 + c4] = *(const float4*)&W1[(size_t)(kc0 + ch*64 + row)*128 + c4];
    }
    __syncthreads();
    for (int kk = 0; kk < 64; kk++) {
      uint4 qa = *(uint4*)&sAt[kk*72 + ty*8];          // 8 bf16 rows
      float4 qb = *(float4*)&sBB[kk*128 + tx*4];
      float ar[8];
      ar[0]=b2lo(qa.x); ar[1]=b2hi(qa.x); ar[2]=b2lo(qa.y); ar[3]=b2hi(qa.y);
      ar[4]=b2lo(qa.z); ar[5]=b2hi(qa.z); ar[6]=b2lo(qa.w); ar[7]=b2hi(qa.w);
      #pragma unroll
      for (int i=0;i<8;i++){
        acc[i][0] += ar[i]*qb.x; acc[i][1] += ar[i]*qb.y;
        acc[i][2] += ar[i]*qb.z; acc[i][3] += ar[i]*qb.w;
      }
    }
    __syncthreads();
  }
  #pragma unroll
  for (int i=0;i<8;i++){
    int gi = g0 + ty*8 + i;
    *(float4*)&partial[(size_t)blockIdx.y*131072 + gi*128 + tx*4] = *(float4*)acc[i];
  }
}

// ---------------- head epilogue: sum slices, bias, leaky, W2 dot, sigmoid ----------------
__global__ __launch_bounds__(64) void head_out(
    const float* __restrict__ partial, const float* __restrict__ b1,
    const float* __restrict__ W2, const float* __restrict__ b2,
    float* __restrict__ out)
{
  const int g = blockIdx.x;
  const int l = threadIdx.x;
  float v0 = b1[l], v1 = b1[64 + l];
  #pragma unroll
  for (int s = 0; s < 16; s++) {
    v0 += partial[(size_t)s*131072 + g*128 + l];
    v1 += partial[(size_t)s*131072 + g*128 + 64 + l];
  }
  float sum = lrelu(v0, 0.01f)*W2[l] + lrelu(v1, 0.01f)*W2[64 + l];
  #pragma unroll
  for (int m = 32; m > 0; m >>= 1) sum += __shfl_xor(sum, m);
  if (l == 0) out[g] = 1.f / (1.f + __expf(-(sum + b2[0])));
}

extern "C" void kernel_launch(void* const* d_in, const int* in_sizes, int n_in,
                              void* d_out, int out_size, void* d_ws, size_t ws_size,
                              hipStream_t stream) {
  const float* x   = (const float*)d_in[0];
  const int*   ei  = (const int*)  d_in[1];
  const float* Wl  = (const float*)d_in[2];
  const float* bl_ = (const float*)d_in[3];
  const float* Wr  = (const float*)d_in[4];
  const float* br_ = (const float*)d_in[5];
  const float* att = (const float*)d_in[6];
  const float* bv2 = (const float*)d_in[7];
  const float* Wg1 = (const float*)d_in[8];
  const float* as1 = (const float*)d_in[9];
  const float* ad1 = (const float*)d_in[10];
  const float* bg1 = (const float*)d_in[11];
  const float* Wg2 = (const float*)d_in[12];
  const float* as2 = (const float*)d_in[13];
  const float* ad2 = (const float*)d_in[14];
  const float* bg2 = (const float*)d_in[15];
  const float* lng = (const float*)d_in[16];
  const float* lnb = (const float*)d_in[17];
  const float* W1  = (const float*)d_in[18];
  const float* b1  = (const float*)d_in[19];
  const float* W2  = (const float*)d_in[20];
  const float* b2  = (const float*)d_in[21];
  float* out = (float*)d_out;

  uint*  hbuf    = (uint*)d_ws;                                   // 1024*4096 u32 = 16 MB (bf16 pairs)
  float* partial = (float*)((char*)d_ws + (size_t)NGRAPH*4096*4); // 16*1024*128 f32 = 8 MB

  gnn_fused<<<NGRAPH, 256, 0, stream>>>(x, ei, Wl, bl_, Wr, br_, att, bv2,
      Wg1, as1, ad1, bg1, Wg2, as2, ad2, bg2, lng, lnb, hbuf);
  head_gemm<<<dim3(16, 16), 256, 0, stream>>>(hbuf, W1, partial);
  head_out<<<NGRAPH, 64, 0, stream>>>(partial, b1, W2, b2, out);
}

// Round 3
// 289.689 us; speedup vs baseline: 2.2620x; 1.2663x over previous
//
#include <hip/hip_runtime.h>
#include <hip/hip_bf16.h>

#define NGRAPH 1024
#define NPG 128
#define NTOT (NGRAPH*NPG)
#define EPG 2048
#define ETOT (NTOT*16)
#define HD 64

typedef unsigned int uint;
typedef unsigned short ushort_t;
typedef __attribute__((ext_vector_type(8))) short s8v;
typedef __attribute__((ext_vector_type(4))) float f32x4;

#define MFMA16 __builtin_amdgcn_mfma_f32_16x16x32_bf16

__device__ __forceinline__ float lrelu(float x, float s){ return fmaxf(x, x*s); }
__device__ __forceinline__ float b2lo(uint u){ return __uint_as_float(u << 16); }
__device__ __forceinline__ float b2hi(uint u){ return __uint_as_float(u & 0xFFFF0000u); }
__device__ __forceinline__ uint pkbf(float a, float b){
  union { __hip_bfloat162 h; uint u; } t;
  t.h = __hip_bfloat162{__float2bfloat16(a), __float2bfloat16(b)};
  return t.u;
}
__device__ __forceinline__ ushort_t bfb(float v){
  __hip_bfloat16 h = __float2bfloat16(v);
  union { __hip_bfloat16 h; ushort_t u; } t; t.h = h; return t.u;
}
union U4S8 { uint4 u; s8v s; };
__device__ __forceinline__ s8v bcs8(uint4 u){ U4S8 t; t.u = u; return t.s; }
__device__ __forceinline__ s8v pk8(uint4 x, uint4 y){
  U4S8 t;
  t.u.x = pkbf(__uint_as_float(x.x), __uint_as_float(x.y));
  t.u.y = pkbf(__uint_as_float(x.z), __uint_as_float(x.w));
  t.u.z = pkbf(__uint_as_float(y.x), __uint_as_float(y.y));
  t.u.w = pkbf(__uint_as_float(y.z), __uint_as_float(y.w));
  return t.s;
}

// DPP add: disabled/invalid source lanes contribute 0 (row_shr 1/2/4 -> sum at lane&7==7)
#define DPP_ADD(v, ctrl) ((v) + __int_as_float(__builtin_amdgcn_update_dpp(0, __float_as_int(v), (ctrl), 0xF, 0xF, false)))

// ROW32: bf16 rows of 64 (32 u32 pairs), octet-XOR swizzle
__device__ __forceinline__ int oswz(int r, int p){ return (r<<5) | ((((p>>2) ^ (r & 7))<<2) | (p & 3)); }
__device__ __forceinline__ int obase(int r, int oc){ return (r<<5) | (((oc) ^ (r & 7))<<2); }
// ROW64: bf16 rows of 128 (64 u32 pairs), 16-row-XOR swizzle
__device__ __forceinline__ int t64(int r, int p){ return (r<<6) | ((((p>>2) ^ (r & 15))<<2) | (p & 3)); }
__device__ __forceinline__ int t64b(int r, int q){ return (r<<6) | (((q ^ (r & 15))<<2)); }
// f32 P-quarter [32][128], 32-quad-XOR swizzle
__device__ __forceinline__ int fP(int r, int k){ return (r<<7) | (((((k>>2) ^ r) & 31)<<2) | (k & 3)); }
__device__ __forceinline__ int fPb(int r, int q){ return (r<<7) | ((((q ^ r) & 31))<<2); }

// LDS map (u32 units)
#define O_A   0        // 4096: xl -> h (sH)      ROW32 [128][32]
#define O_B   4096     // 4096: xr -> xlT / XwT   ROW32 [128][32] / ROW64 [64][64]
#define O_P   8192     // 4096: P quarter f32 [32][128]
#define O_E   12288    // 2048: eva f32 [2048] / WgT ROW32 [64][32]
#define O_ED  14336    // 1024: edsd u16 [2048]
#define O_SOF 15360    // 129
#define O_SPO 15489    // 128
#define O_NMV 15617    // 128
#define O_SSE 15745    // 128
#define O_ALS 15873    // 128
#define O_ALD 16001    // 128
#define O_WAS 16132    // 64 (16B aligned)
#define O_WAD 16196    // 64
#define SM_SZ 16260    // 65040 B static LDS -> 2 blocks/CU

__global__ __launch_bounds__(256) void gnn_fused(
    const float* __restrict__ x, const int* __restrict__ ei,
    const float* __restrict__ Wl, const float* __restrict__ bl,
    const float* __restrict__ Wr, const float* __restrict__ br,
    const float* __restrict__ att, const float* __restrict__ bv2,
    const float* __restrict__ Wg1, const float* __restrict__ as1,
    const float* __restrict__ ad1, const float* __restrict__ bg1,
    const float* __restrict__ Wg2, const float* __restrict__ as2,
    const float* __restrict__ ad2, const float* __restrict__ bg2,
    const float* __restrict__ lng, const float* __restrict__ lnb,
    uint* __restrict__ hout)
{
  __shared__ uint SM[SM_SZ];
  uint*     sXl  = SM + O_A;                  // xl / sH
  uint*     sXr  = SM + O_B;                  // xr / xlT / XwT
  float*    Pf   = (float*)(SM + O_P);
  float*    eva  = (float*)(SM + O_E);
  ushort_t* edsd = (ushort_t*)(SM + O_ED);
  int*      soff = (int*)(SM + O_SOF);
  int*      spos = (int*)(SM + O_SPO);
  float*    nmv  = (float*)(SM + O_NMV);
  float*    sse  = (float*)(SM + O_SSE);
  float*    als  = (float*)(SM + O_ALS);
  float*    ald  = (float*)(SM + O_ALD);
  float*    was  = (float*)(SM + O_WAS);
  float*    wad  = (float*)(SM + O_WAD);
  ushort_t* sH16 = (ushort_t*)(SM + O_A);
  ushort_t* sT16 = (ushort_t*)(SM + O_B);
  ushort_t* wg16 = (ushort_t*)(SM + O_E);

  const int g    = blockIdx.x;
  const int tid  = threadIdx.x;
  const int lane = tid & 63;
  const int wv   = tid >> 6;
  const int lw   = lane & 15;      // MFMA: col/row low
  const int lq   = lane >> 4;      // MFMA: quad
  const int oc   = lane & 7;       // octet within 64-feat row
  const int ebase = g * EPG;

  // ---------------- CSR build ----------------
  if (tid < NPG) spos[tid] = 0;
  __syncthreads();
  for (int e = tid; e < EPG; e += 256)
    atomicAdd(&spos[ei[ETOT + ebase + e] - g*NPG], 1);
  __syncthreads();
  if (wv == 0) {
    int c0 = spos[lane], c1 = spos[lane + 64];
    #pragma unroll
    for (int o = 1; o < 64; o <<= 1) { int t = __shfl_up(c0, o); if (lane >= o) c0 += t; }
    #pragma unroll
    for (int o = 1; o < 64; o <<= 1) { int t = __shfl_up(c1, o); if (lane >= o) c1 += t; }
    int tot0 = __shfl(c0, 63);
    soff[lane + 1]  = c0;
    soff[lane + 65] = c1 + tot0;
    if (lane == 0) soff[0] = 0;
  }
  __syncthreads();
  if (tid < NPG) spos[tid] = soff[tid];
  __syncthreads();
  for (int e = tid; e < EPG; e += 256) {
    int s = ei[ebase + e] - g*NPG;
    int d = ei[ETOT + ebase + e] - g*NPG;
    int p = atomicAdd(&spos[d], 1);
    edsd[p] = (ushort_t)(s | (d << 8));
  }

  // ---------------- GATv2 transforms: xl -> sXl (bf16), xr -> sXr (bf16) ----------------
  {
    const int pl = lane & 31, hb = lane >> 5;
    const float2 wl0 = *(const float2*)&Wl[0*64 + 2*pl];
    const float2 wl1 = *(const float2*)&Wl[1*64 + 2*pl];
    const float2 wl2 = *(const float2*)&Wl[2*64 + 2*pl];
    const float2 wl3 = *(const float2*)&Wl[3*64 + 2*pl];
    const float2 wr0 = *(const float2*)&Wr[0*64 + 2*pl];
    const float2 wr1 = *(const float2*)&Wr[1*64 + 2*pl];
    const float2 wr2 = *(const float2*)&Wr[2*64 + 2*pl];
    const float2 wr3 = *(const float2*)&Wr[3*64 + 2*pl];
    const float2 blp = *(const float2*)&bl[2*pl];
    const float2 brp = *(const float2*)&br[2*pl];
    const float4* x4 = (const float4*)x + (size_t)g * NPG;
    __syncthreads();   // covers CSR scatter
    for (int st = 0; st < 16; st++) {
      int i = st*8 + wv*2 + hb;
      float4 xi = x4[i];
      float l0 = blp.x + xi.x*wl0.x + xi.y*wl1.x + xi.z*wl2.x + xi.w*wl3.x;
      float l1 = blp.y + xi.x*wl0.y + xi.y*wl1.y + xi.z*wl2.y + xi.w*wl3.y;
      float r0 = brp.x + xi.x*wr0.x + xi.y*wr1.x + xi.z*wr2.x + xi.w*wr3.x;
      float r1 = brp.y + xi.x*wr0.y + xi.y*wr1.y + xi.z*wr2.y + xi.w*wr3.y;
      sXl[oswz(i, pl)] = pkbf(l0, l1);
      sXr[oswz(i, pl)] = pkbf(r0, r1);
    }
  }
  __syncthreads();

  // ---------------- GATv2 edge logits (8-lane groups, b128 bf16 gathers) ----------------
  {
    const int grp = lane >> 3;
    float4 atA = *(const float4*)&att[oc*8];
    float4 atB = *(const float4*)&att[oc*8 + 4];
    int base = wv * 512;
    for (int stp = 0; stp < 64; stp++) {
      int e  = base + stp*8 + grp;
      int sd = edsd[e];
      int s  = sd & 127, d = sd >> 8;
      uint4 ql = *(uint4*)&sXl[obase(s, oc)];
      uint4 qr = *(uint4*)&sXr[obase(d, oc)];
      float acc, v;
      v = b2lo(ql.x)+b2lo(qr.x); acc  = lrelu(v,0.2f)*atA.x;
      v = b2hi(ql.x)+b2hi(qr.x); acc += lrelu(v,0.2f)*atA.y;
      v = b2lo(ql.y)+b2lo(qr.y); acc += lrelu(v,0.2f)*atA.z;
      v = b2hi(ql.y)+b2hi(qr.y); acc += lrelu(v,0.2f)*atA.w;
      v = b2lo(ql.z)+b2lo(qr.z); acc += lrelu(v,0.2f)*atB.x;
      v = b2hi(ql.z)+b2hi(qr.z); acc += lrelu(v,0.2f)*atB.y;
      v = b2lo(ql.w)+b2lo(qr.w); acc += lrelu(v,0.2f)*atB.z;
      v = b2hi(ql.w)+b2hi(qr.w); acc += lrelu(v,0.2f)*atB.w;
      acc = DPP_ADD(acc, 0x111); acc = DPP_ADD(acc, 0x112); acc = DPP_ADD(acc, 0x114);
      if ((lane & 7) == 7) eva[e] = acc;
    }
  }
  __syncthreads();

  // ---------------- GATv2 softmax (no self) + transpose xl -> xlT ----------------
  {
    const int g16 = tid >> 4, sl = tid & 15;
    for (int it = 0; it < 8; it++) {
      int d = it*16 + g16;
      int p0 = soff[d], p1 = soff[d+1];
      float m = -1e30f;
      for (int p = p0 + sl; p < p1; p += 16) m = fmaxf(m, eva[p]);
      #pragma unroll
      for (int o = 1; o < 16; o <<= 1) m = fmaxf(m, __shfl_xor(m, o));
      float ssum = 0.f;
      for (int p = p0 + sl; p < p1; p += 16) {
        float ex = __expf(eva[p] - m); ssum += ex; eva[p] = ex;
      }
      #pragma unroll
      for (int o = 1; o < 16; o <<= 1) ssum += __shfl_xor(ssum, o);
      if (sl == 0) nmv[d] = 1.f / (ssum + 1e-16f);
    }
    // transpose xl (ROW32 [s][j]) -> xlT (ROW64 [j][s]) ; xr is dead
    ushort_t* xl16 = (ushort_t*)(SM + O_A);
    int j = tid & 63, spb = tid >> 6;
    for (int i = 0; i < 16; i++) {
      int sp = spb*16 + i;
      float v0 = __uint_as_float((uint)xl16[oswz(2*sp,   j>>1)*2 + (j&1)] << 16);
      float v1 = __uint_as_float((uint)xl16[oswz(2*sp+1, j>>1)*2 + (j&1)] << 16);
      sXr[t64(j, sp)] = pkbf(v0, v1);
    }
  }
  __syncthreads();

  // ---------------- GATv2 aggregate: 4 quarters of dense P @ xlT via MFMA ----------------
  {
    int n0 = 32*(wv>>1), m0 = 16*(wv&1);
    float bja = bv2[n0 + lw], bjb = bv2[n0 + 16 + lw];
    for (int q = 0; q < 4; q++) {
      #pragma unroll
      for (int i = 0; i < 4; i++) { uint4 z = {0,0,0,0}; *(uint4*)&SM[O_P + (tid + i*256)*4] = z; }
      __syncthreads();
      int p0 = soff[q*32], p1 = soff[q*32 + 32];
      for (int p = p0 + tid; p < p1; p += 256) {
        int sd = edsd[p]; int s = sd & 127, d = sd >> 8;
        atomicAdd(&Pf[fP(d - q*32, s)], eva[p] * nmv[d]);
      }
      __syncthreads();
      f32x4 c0 = {0.f,0.f,0.f,0.f}, c1 = {0.f,0.f,0.f,0.f};
      int row = m0 + lw;
      #pragma unroll
      for (int ks = 0; ks < 4; ks++) {
        int kk = ks*32 + lq*8;
        uint4 f0 = *(uint4*)&Pf[fPb(row, kk>>2)];
        uint4 f1 = *(uint4*)&Pf[fPb(row, (kk>>2)+1)];
        s8v a = pk8(f0, f1);
        s8v b0 = bcs8(*(uint4*)&SM[O_B + t64b(n0 + lw,      kk>>3)]);
        s8v b1 = bcs8(*(uint4*)&SM[O_B + t64b(n0 + 16 + lw, kk>>3)]);
        c0 = MFMA16(a, b0, c0, 0, 0, 0);
        c1 = MFMA16(a, b1, c1, 0, 0, 0);
      }
      int rg0 = q*32 + m0 + lq*4;
      #pragma unroll
      for (int rg = 0; rg < 4; rg++) {
        float v0 = lrelu(c0[rg] + bja, 0.01f);
        float v1 = lrelu(c1[rg] + bjb, 0.01f);
        int jc0 = n0 + lw, jc1 = n0 + 16 + lw;
        sH16[oswz(rg0+rg, jc0>>1)*2 + (jc0&1)] = bfb(v0);
        sH16[oswz(rg0+rg, jc1>>1)*2 + (jc1&1)] = bfb(v1);
      }
      __syncthreads();
    }
  }

  // ---------------- LayerNorm in place on sH (bf16) ----------------
  {
    int pl = lane & 31, hb = lane >> 5;
    float2 gv = *(const float2*)&lng[2*pl];
    float2 bv = *(const float2*)&lnb[2*pl];
    for (int it = 0; it < 16; it++) {
      int d = it*8 + wv*2 + hb;
      uint w = SM[O_A + oswz(d, pl)];
      float v0 = b2lo(w), v1 = b2hi(w);
      float s1 = v0 + v1, s2 = v0*v0 + v1*v1;
      #pragma unroll
      for (int o = 1; o < 32; o <<= 1) { s1 += __shfl_xor(s1, o); s2 += __shfl_xor(s2, o); }
      float mu  = s1 * 0.015625f;
      float var = s2 * 0.015625f - mu*mu;
      float rs  = rsqrtf(var + 1e-5f);
      v0 = (v0 - mu)*rs*gv.x + bv.x;
      v1 = (v1 - mu)*rs*gv.y + bv.y;
      SM[O_A + oswz(d, pl)] = pkbf(v0, v1);
    }
  }
  __syncthreads();

  // ---------------- two GATConv layers ----------------
  for (int layer = 0; layer < 2; layer++) {
    const float* Wg  = layer ? Wg2 : Wg1;
    const float* avs = layer ? as2 : as1;
    const float* avd = layer ? ad2 : ad1;
    const float* bg  = layer ? bg2 : bg1;

    // stage: waves 0,1 -> wa_s/wa_d = Wg @ a ; waves 2,3 -> WgT bf16 (O_E)
    if (tid < 128) {
      const float* av = (tid < 64) ? avs : avd;
      float* dst = (tid < 64) ? was : wad;
      int k = tid & 63;
      float acc = 0.f;
      #pragma unroll
      for (int jj = 0; jj < 16; jj++) {
        float4 w = *(const float4*)&Wg[k*64 + jj*4];
        float4 a = *(const float4*)&av[jj*4];
        acc += w.x*a.x + w.y*a.y + w.z*a.z + w.w*a.w;
      }
      dst[k] = acc;
    } else {
      int t2 = tid - 128;
      #pragma unroll
      for (int i = 0; i < 8; i++) {
        int idx = t2 + i*128;
        int k = idx >> 4, j4 = (idx & 15)*4;
        float4 w = *(const float4*)&Wg[k*64 + j4];
        wg16[oswz(j4+0, k>>1)*2 + (k&1)] = bfb(w.x);
        wg16[oswz(j4+1, k>>1)*2 + (k&1)] = bfb(w.y);
        wg16[oswz(j4+2, k>>1)*2 + (k&1)] = bfb(w.z);
        wg16[oswz(j4+3, k>>1)*2 + (k&1)] = bfb(w.w);
      }
    }
    __syncthreads();

    // transform MFMA: XwT[j][d] = (h @ Wg)^T ; A = WgT (O_E), B = sH rows
    {
      int row = 16*wv + lw;   // j-row of A
      s8v a0 = bcs8(*(uint4*)&SM[O_E + obase(row, lq)]);
      s8v a1 = bcs8(*(uint4*)&SM[O_E + obase(row, 4+lq)]);
      #pragma unroll
      for (int nt = 0; nt < 8; nt++) {
        int d = nt*16 + lw;
        s8v b0 = bcs8(*(uint4*)&SM[O_A + obase(d, lq)]);
        s8v b1 = bcs8(*(uint4*)&SM[O_A + obase(d, 4+lq)]);
        f32x4 c = {0.f,0.f,0.f,0.f};
        c = MFMA16(a0, b0, c, 0, 0, 0);
        c = MFMA16(a1, b1, c, 0, 0, 0);
        int j0 = 16*wv + lq*4;
        #pragma unroll
        for (int rg = 0; rg < 4; rg++)
          sT16[t64(j0+rg, d>>1)*2 + (d&1)] = bfb(c[rg]);
      }
    }
    __syncthreads();

    // als/ald = h @ wa  (8-lane groups, DPP reduce)
    {
      float4 ws0 = *(float4*)&was[oc*8], ws1 = *(float4*)&was[oc*8 + 4];
      float4 wd0 = *(float4*)&wad[oc*8], wd1 = *(float4*)&wad[oc*8 + 4];
      for (int ps = 0; ps < 4; ps++) {
        int n = ps*32 + (tid >> 3);
        uint4 q = *(uint4*)&SM[O_A + obase(n, oc)];
        float f0=b2lo(q.x), f1=b2hi(q.x), f2=b2lo(q.y), f3=b2hi(q.y);
        float f4=b2lo(q.z), f5=b2hi(q.z), f6=b2lo(q.w), f7=b2hi(q.w);
        float sa = f0*ws0.x+f1*ws0.y+f2*ws0.z+f3*ws0.w+f4*ws1.x+f5*ws1.y+f6*ws1.z+f7*ws1.w;
        float sd = f0*wd0.x+f1*wd0.y+f2*wd0.z+f3*wd0.w+f4*wd1.x+f5*wd1.y+f6*wd1.z+f7*wd1.w;
        sa = DPP_ADD(sa, 0x111); sa = DPP_ADD(sa, 0x112); sa = DPP_ADD(sa, 0x114);
        sd = DPP_ADD(sd, 0x111); sd = DPP_ADD(sd, 0x112); sd = DPP_ADD(sd, 0x114);
        if ((lane & 7) == 7) { als[n] = sa; ald[n] = sd; }
      }
    }
    __syncthreads();

    // edge logits (rank-1)
    #pragma unroll
    for (int i = 0; i < 8; i++) {
      int e = tid + i*256;
      int sd = edsd[e];
      eva[e] = lrelu(als[sd & 127] + ald[sd >> 8], 0.2f);
    }
    __syncthreads();

    // softmax incl self-loop
    {
      const int g16 = tid >> 4, sl = tid & 15;
      for (int it = 0; it < 8; it++) {
        int d = it*16 + g16;
        int p0 = soff[d], p1 = soff[d+1];
        float se = lrelu(als[d] + ald[d], 0.2f);
        float m = se;
        for (int p = p0 + sl; p < p1; p += 16) m = fmaxf(m, eva[p]);
        #pragma unroll
        for (int o = 1; o < 16; o <<= 1) m = fmaxf(m, __shfl_xor(m, o));
        float ex0 = __expf(se - m);
        float ssum = 0.f;
        for (int p = p0 + sl; p < p1; p += 16) {
          float ex = __expf(eva[p] - m); ssum += ex; eva[p] = ex;
        }
        #pragma unroll
        for (int o = 1; o < 16; o <<= 1) ssum += __shfl_xor(ssum, o);
        if (sl == 0) { nmv[d] = 1.f / (ssum + ex0 + 1e-16f); sse[d] = ex0; }
      }
    }
    __syncthreads();

    // aggregate: 4 quarters of dense P @ XwT via MFMA (+self), bias+relu -> sH
    {
      int n0 = 32*(wv>>1), m0 = 16*(wv&1);
      float bja = bg[n0 + lw], bjb = bg[n0 + 16 + lw];
      for (int q = 0; q < 4; q++) {
        #pragma unroll
        for (int i = 0; i < 4; i++) { uint4 z = {0,0,0,0}; *(uint4*)&SM[O_P + (tid + i*256)*4] = z; }
        __syncthreads();
        int p0 = soff[q*32], p1 = soff[q*32 + 32];
        for (int p = p0 + tid; p < p1; p += 256) {
          int sd = edsd[p]; int s = sd & 127, d = sd >> 8;
          atomicAdd(&Pf[fP(d - q*32, s)], eva[p] * nmv[d]);
        }
        if (tid < 32) { int d = q*32 + tid; atomicAdd(&Pf[fP(tid, d)], sse[d] * nmv[d]); }
        __syncthreads();
        f32x4 c0 = {0.f,0.f,0.f,0.f}, c1 = {0.f,0.f,0.f,0.f};
        int row = m0 + lw;
        #pragma unroll
        for (int ks = 0; ks < 4; ks++) {
          int kk = ks*32 + lq*8;
          uint4 f0 = *(uint4*)&Pf[fPb(row, kk>>2)];
          uint4 f1 = *(uint4*)&Pf[fPb(row, (kk>>2)+1)];
          s8v a = pk8(f0, f1);
          s8v b0 = bcs8(*(uint4*)&SM[O_B + t64b(n0 + lw,      kk>>3)]);
          s8v b1 = bcs8(*(uint4*)&SM[O_B + t64b(n0 + 16 + lw, kk>>3)]);
          c0 = MFMA16(a, b0, c0, 0, 0, 0);
          c1 = MFMA16(a, b1, c1, 0, 0, 0);
        }
        int rg0 = q*32 + m0 + lq*4;
        #pragma unroll
        for (int rg = 0; rg < 4; rg++) {
          float v0 = fmaxf(c0[rg] + bja, 0.f);
          float v1 = fmaxf(c1[rg] + bjb, 0.f);
          int jc0 = n0 + lw, jc1 = n0 + 16 + lw;
          sH16[oswz(rg0+rg, jc0>>1)*2 + (jc0&1)] = bfb(v0);
          sH16[oswz(rg0+rg, jc1>>1)*2 + (jc1&1)] = bfb(v1);
        }
        __syncthreads();
      }
    }
  }

  // ---------------- write h (bf16 pairs, node-major) ----------------
  {
    uint* hg = hout + (size_t)g * 4096;
    #pragma unroll
    for (int i = 0; i < 16; i++) {
      int idx = tid + i*256;
      hg[idx] = SM[O_A + oswz(idx >> 5, idx & 31)];
    }
  }
}

// ---------------- W1 -> W1T bf16 pair transpose ----------------
__global__ __launch_bounds__(256) void w1_transpose(const float* __restrict__ W1,
                                                    uint* __restrict__ w1t)
{
  __shared__ float sw[64*130];
  const int tid = threadIdx.x;
  const int k0 = blockIdx.x * 64;
  #pragma unroll
  for (int i = 0; i < 8; i++) {
    int idx = tid + i*256;
    int r = idx >> 5, c4 = (idx & 31)*4;
    *(float4*)&sw[r*130 + c4] = *(const float4*)&W1[(size_t)(k0+r)*128 + c4];
  }
  __syncthreads();
  #pragma unroll
  for (int i = 0; i < 16; i++) {
    int idx = tid + i*256;
    int c = idx >> 5, kp = idx & 31;
    w1t[(size_t)c*4096 + (k0>>1) + kp] = pkbf(sw[(2*kp)*130 + c], sw[(2*kp+1)*130 + c]);
  }
}

// ---------------- head GEMM: MFMA, split-K 16 ----------------
__global__ __launch_bounds__(256) void head_gemm(
    const uint* __restrict__ hbuf, const uint* __restrict__ w1t,
    float* __restrict__ partial)
{
  __shared__ uint sAh[2048];   // [64 g][32 pairs]
  __shared__ uint sBh[4096];   // [128 c][32 pairs]
  const int tid = threadIdx.x, lane = tid & 63, wv = tid >> 6;
  const int lw = lane & 15, lq = lane >> 4;
  const int g0 = blockIdx.x * 64;
  const int ks = blockIdx.y;
  f32x4 acc[8];
  #pragma unroll
  for (int i = 0; i < 8; i++) acc[i] = f32x4{0.f,0.f,0.f,0.f};

  for (int ch = 0; ch < 8; ch++) {
    int pb = ks*256 + ch*32;
    #pragma unroll
    for (int i = 0; i < 2; i++) {
      int idx = tid + i*256; int r = idx >> 3, q4 = idx & 7;
      uint4 v = *(const uint4*)&hbuf[(size_t)(g0+r)*4096 + pb + q4*4];
      *(uint4*)&sAh[(r<<5) | ((q4 ^ (r & 7))<<2)] = v;
    }
    #pragma unroll
    for (int i = 0; i < 4; i++) {
      int idx = tid + i*256; int r = idx >> 3, q4 = idx & 7;
      uint4 v = *(const uint4*)&w1t[(size_t)r*4096 + pb + q4*4];
      *(uint4*)&sBh[(r<<5) | ((q4 ^ (r & 7))<<2)] = v;
    }
    __syncthreads();
    int ra = 16*wv + lw;
    s8v a0 = bcs8(*(uint4*)&sAh[obase(ra, lq)]);
    s8v a1 = bcs8(*(uint4*)&sAh[obase(ra, 4+lq)]);
    #pragma unroll
    for (int nt = 0; nt < 8; nt++) {
      int c = nt*16 + lw;
      s8v b0 = bcs8(*(uint4*)&sBh[obase(c, lq)]);
      s8v b1 = bcs8(*(uint4*)&sBh[obase(c, 4+lq)]);
      acc[nt] = MFMA16(a0, b0, acc[nt], 0, 0, 0);
      acc[nt] = MFMA16(a1, b1, acc[nt], 0, 0, 0);
    }
    __syncthreads();
  }
  float* pp = partial + (size_t)ks*131072;
  #pragma unroll
  for (int nt = 0; nt < 8; nt++) {
    int c = nt*16 + lw;
    int r0 = g0 + 16*wv + lq*4;
    #pragma unroll
    for (int rg = 0; rg < 4; rg++)
      pp[(size_t)(r0+rg)*128 + c] = acc[nt][rg];
  }
}

// ---------------- head epilogue ----------------
__global__ __launch_bounds__(64) void head_out(
    const float* __restrict__ partial, const float* __restrict__ b1,
    const float* __restrict__ W2, const float* __restrict__ b2,
    float* __restrict__ out)
{
  const int g = blockIdx.x;
  const int l = threadIdx.x;
  float v0 = b1[l], v1 = b1[64 + l];
  #pragma unroll
  for (int s = 0; s < 16; s++) {
    v0 += partial[(size_t)s*131072 + g*128 + l];
    v1 += partial[(size_t)s*131072 + g*128 + 64 + l];
  }
  float sum = lrelu(v0, 0.01f)*W2[l] + lrelu(v1, 0.01f)*W2[64 + l];
  #pragma unroll
  for (int m = 32; m > 0; m >>= 1) sum += __shfl_xor(sum, m);
  if (l == 0) out[g] = 1.f / (1.f + __expf(-(sum + b2[0])));
}

extern "C" void kernel_launch(void* const* d_in, const int* in_sizes, int n_in,
                              void* d_out, int out_size, void* d_ws, size_t ws_size,
                              hipStream_t stream) {
  const float* x   = (const float*)d_in[0];
  const int*   ei  = (const int*)  d_in[1];
  const float* Wl  = (const float*)d_in[2];
  const float* bl_ = (const float*)d_in[3];
  const float* Wr  = (const float*)d_in[4];
  const float* br_ = (const float*)d_in[5];
  const float* att = (const float*)d_in[6];
  const float* bv2 = (const float*)d_in[7];
  const float* Wg1 = (const float*)d_in[8];
  const float* as1 = (const float*)d_in[9];
  const float* ad1 = (const float*)d_in[10];
  const float* bg1 = (const float*)d_in[11];
  const float* Wg2 = (const float*)d_in[12];
  const float* as2 = (const float*)d_in[13];
  const float* ad2 = (const float*)d_in[14];
  const float* bg2 = (const float*)d_in[15];
  const float* lng = (const float*)d_in[16];
  const float* lnb = (const float*)d_in[17];
  const float* W1  = (const float*)d_in[18];
  const float* b1  = (const float*)d_in[19];
  const float* W2  = (const float*)d_in[20];
  const float* b2  = (const float*)d_in[21];
  float* out = (float*)d_out;

  uint*  hbuf    = (uint*)d_ws;                                      // 16 MB
  float* partial = (float*)((char*)d_ws + (size_t)16*1024*1024);     // 8 MB
  uint*  w1t     = (uint*)((char*)d_ws + (size_t)24*1024*1024);      // 2 MB

  w1_transpose<<<128, 256, 0, stream>>>(W1, w1t);
  gnn_fused<<<NGRAPH, 256, 0, stream>>>(x, ei, Wl, bl_, Wr, br_, att, bv2,
      Wg1, as1, ad1, bg1, Wg2, as2, ad2, bg2, lng, lnb, hbuf);
  head_gemm<<<dim3(16, 16), 256, 0, stream>>>(hbuf, w1t, partial);
  head_out<<<NGRAPH, 64, 0, stream>>>(partial, b1, W2, b2, out);
}